// Round 4
// baseline (309.338 us; speedup 1.0000x reference)
//
#include <hip/hip_runtime.h>

#define BB 65536
#define TT 20
#define HH 10
#define EPB 64
#define NW  5                 // waves/block; wave w owns units {2w, 2w+1}
#define NBLK (BB / EPB)       // 1024 blocks = 4/CU * 256 CUs exactly

typedef __fp16 h2v __attribute__((ext_vector_type(2)));

__device__ __forceinline__ float sigmoid_f(float x) {
    float t = __builtin_amdgcn_exp2f(-1.44269504f * x);   // e^-x
    return __builtin_amdgcn_rcpf(1.0f + t);
}
__device__ __forceinline__ float tanh_f(float x) {
    float t = __builtin_amdgcn_exp2f(2.88539008f * x);    // e^(2x)
    return 1.0f - 2.0f * __builtin_amdgcn_rcpf(t + 1.0f);
}
__device__ __forceinline__ unsigned pk_h16(float a, float b) {
    h2v v = __builtin_amdgcn_cvt_pkrtz(a, b);             // 2xfp16 pack (RTZ)
    return __builtin_bit_cast(unsigned, v);
}
__device__ __forceinline__ float2 unpk_h16(unsigned u) {
    h2v v = __builtin_bit_cast(h2v, u);
    return make_float2((float)v[0], (float)v[1]);
}

template<bool WS> struct LdsBuf {
    unsigned      x6[TT][3][EPB];          // 15360  x (6ch) fp16 pairs
    float2        hbx[2][NW][EPB];         //  5120  h exchange, dbuf by t-parity
    float2        h1x[2][NW][EPB];         //  5120  h1 exchange, dbuf
    unsigned char msk[TT][EPB];            //  1280
    unsigned      hf0[WS ? 1 : TT][NW][EPB];  // fp16 pairs (LDS only in fallback)
};  // WS=true: 28160 B -> 4+ blocks/CU ; WS=false: 52480 B -> 3 blocks/CU

template<int KIN, int LDI>
__device__ __forceinline__ void gates8(
    const float* __restrict__ wih, const float* __restrict__ whh,
    const float* bias8, const float* xin, const float* hin, int u0, float* a8)
{
#pragma unroll
    for (int q = 0; q < 4; ++q) {                 // gate type i,f,g,o
#pragma unroll
        for (int s = 0; s < 2; ++s) {             // sub-unit
            const int r = q * HH + u0 + s;        // wave-uniform row -> s_loads
            float acc = bias8[q * 2 + s];
            const float* wi = wih + r * LDI;
#pragma unroll
            for (int k = 0; k < KIN; ++k) acc = fmaf(wi[k], xin[k], acc);
            const float* wh = whh + r * HH;
#pragma unroll
            for (int j = 0; j < HH; ++j) acc = fmaf(wh[j], hin[j], acc);
            a8[q * 2 + s] = acc;
        }
    }
}

__device__ __forceinline__ float2 cell_update(const float* a8, float* c) {
    float iv0 = sigmoid_f(a8[0]), fv0 = sigmoid_f(a8[2]);
    float gv0 = tanh_f(a8[4]),    ov0 = sigmoid_f(a8[6]);
    c[0] = fmaf(fv0, c[0], iv0 * gv0);
    float h0 = ov0 * tanh_f(c[0]);
    float iv1 = sigmoid_f(a8[1]), fv1 = sigmoid_f(a8[3]);
    float gv1 = tanh_f(a8[5]),    ov1 = sigmoid_f(a8[7]);
    c[1] = fmaf(fv1, c[1], iv1 * gv1);
    float h1 = ov1 * tanh_f(c[1]);
    return make_float2(h0, h1);
}

template<bool WS>
__global__ __launch_bounds__(NW * 64, 6)
void bilstm_unit_split(
    const int*   __restrict__ e,    const float* __restrict__ f,
    const float* __restrict__ emb,  const float* __restrict__ fw,
    const float* __restrict__ fb,
    const float* __restrict__ wih0, const float* __restrict__ whh0,
    const float* __restrict__ bih0, const float* __restrict__ bhh0,
    const float* __restrict__ wih0r,const float* __restrict__ whh0r,
    const float* __restrict__ bih0r,const float* __restrict__ bhh0r,
    const float* __restrict__ wih1r,const float* __restrict__ whh1r,
    const float* __restrict__ bih1r,const float* __restrict__ bhh1r,
    unsigned* __restrict__ gws, float* __restrict__ out)
{
    __shared__ LdsBuf<WS> lds;
    const int tid  = threadIdx.x;
    const int lane = tid & 63;
    const int wu   = __builtin_amdgcn_readfirstlane(tid >> 6);
    const int bid  = blockIdx.x;
    const int b0   = bid * EPB;
    const int u0   = 2 * wu;

    // ---------------- Stage x (direct coalesced global reads) ----------------
    {
        float fw0=fw[0],fw1=fw[1],fw2=fw[2],fw3=fw[3],fw4=fw[4];
        float fw5=fw[5],fw6=fw[6],fw7=fw[7],fw8=fw[8];
        float fb0=fb[0],fb1=fb[1],fb2=fb[2];
#pragma unroll
        for (int it = 0; it < (EPB * TT) / (NW * 64); ++it) {
            int p = tid + it * NW * 64;          // p = elem*TT + t
            int elem = p / TT, t = p - elem * TT;
            float f0  = f[b0 * TT * 3 + p * 3 + 0];
            float f1  = f[b0 * TT * 3 + p * 3 + 1];
            float f2v = f[b0 * TT * 3 + p * 3 + 2];
            int   ei  = e[b0 * TT + p] * 3;
            float x0 = emb[ei], x1 = emb[ei + 1], x2 = emb[ei + 2];
            float x3 = fmaf(fw0, f0, fmaf(fw1, f1, fmaf(fw2, f2v, fb0)));
            float x4 = fmaf(fw3, f0, fmaf(fw4, f1, fmaf(fw5, f2v, fb1)));
            float x5 = fmaf(fw6, f0, fmaf(fw7, f1, fmaf(fw8, f2v, fb2)));
            lds.x6[t][0][elem] = pk_h16(x0, x1);
            lds.x6[t][1][elem] = pk_h16(x2, x3);
            lds.x6[t][2][elem] = pk_h16(x4, x5);
            lds.msk[t][elem]   = (f1 != 0.0f) ? 1 : 0;
        }
        lds.hbx[1][wu][lane] = make_float2(0.f, 0.f);   // h(-1) = 0 (t=0 reads parity 1)
        lds.h1x[0][wu][lane] = make_float2(0.f, 0.f);   // h1(20) = 0 (t=19 reads parity 0)
    }
    __syncthreads();

    // Per-wave fused biases (uniform -> SGPRs)
    float bs0[8], bs0r[8], bs1[8];
#pragma unroll
    for (int q = 0; q < 4; ++q)
#pragma unroll
        for (int s = 0; s < 2; ++s) {
            int r = q * HH + u0 + s;
            bs0 [q * 2 + s] = bih0 [r] + bhh0 [r];
            bs0r[q * 2 + s] = bih0r[r] + bhh0r[r];
            bs1 [q * 2 + s] = bih1r[r] + bhh1r[r];
        }

    // ---------------- Phase 1: layer-0 forward (1 barrier/t) ----------------
    {
        float c01[2] = {0.f, 0.f};
#pragma unroll 1
        for (int t = 0; t < TT; ++t) {
            const int p = t & 1;
            float hin[10];
#pragma unroll
            for (int j = 0; j < NW; ++j) {
                float2 hp = lds.hbx[p ^ 1][j][lane];
                hin[2 * j] = hp.x; hin[2 * j + 1] = hp.y;
            }
            float xin[6];
#pragma unroll
            for (int j = 0; j < 3; ++j) {
                float2 xp = unpk_h16(lds.x6[t][j][lane]);
                xin[2 * j] = xp.x; xin[2 * j + 1] = xp.y;
            }
            float a8[8];
            gates8<6, 6>(wih0, whh0, bs0, xin, hin, u0, a8);
            float2 hp = cell_update(a8, c01);
            lds.hbx[p][wu][lane] = hp;
            unsigned hu = pk_h16(hp.x, hp.y);
            if (WS) gws[((bid * TT + t) * NW + wu) * EPB + lane] = hu;
            else    lds.hf0[t][wu][lane] = hu;
            __syncthreads();
        }
    }
    lds.hbx[0][wu][lane] = make_float2(0.f, 0.f);   // hb(20) = 0 for phase 2
    __syncthreads();

    // ------ Phase 2: fused layer-0 backward + layer-1 backward (2 barriers/t) ------
    {
        float cb[2] = {0.f, 0.f}, cc[2] = {0.f, 0.f};
        float tot = 0.f;
#pragma unroll 1
        for (int t = TT - 1; t >= 0; --t) {
            const int p = t & 1, pq = p ^ 1;
            unsigned hfu[NW];
            if (WS) {   // prefetch hf0[t] early; vmcnt-waited at use in cellB
#pragma unroll
                for (int j = 0; j < NW; ++j)
                    hfu[j] = gws[((bid * TT + t) * NW + j) * EPB + lane];
            }
            // ---- cellA: layer-0 backward ----
            float hin[10];
#pragma unroll
            for (int j = 0; j < NW; ++j) {
                float2 hp = lds.hbx[pq][j][lane];
                hin[2 * j] = hp.x; hin[2 * j + 1] = hp.y;
            }
            float xin[6];
#pragma unroll
            for (int j = 0; j < 3; ++j) {
                float2 xp = unpk_h16(lds.x6[t][j][lane]);
                xin[2 * j] = xp.x; xin[2 * j + 1] = xp.y;
            }
            float a8[8];
            gates8<6, 6>(wih0r, whh0r, bs0r, xin, hin, u0, a8);
            float2 hbp = cell_update(a8, cb);
            lds.hbx[p][wu][lane] = hbp;
            __syncthreads();

            // ---- cellB: layer-1 backward, input = [hf0(t), hb(t)] ----
            if (!WS) {
#pragma unroll
                for (int j = 0; j < NW; ++j) hfu[j] = lds.hf0[t][j][lane];
            }
            float xin2[20];
#pragma unroll
            for (int j = 0; j < NW; ++j) {
                float2 xh = unpk_h16(hfu[j]);
                xin2[2 * j] = xh.x; xin2[2 * j + 1] = xh.y;
            }
#pragma unroll
            for (int j = 0; j < NW; ++j) {
                float2 hb = lds.hbx[p][j][lane];
                xin2[10 + 2 * j] = hb.x; xin2[10 + 2 * j + 1] = hb.y;
            }
            float h1in[10];
#pragma unroll
            for (int j = 0; j < NW; ++j) {
                float2 hp = lds.h1x[pq][j][lane];
                h1in[2 * j] = hp.x; h1in[2 * j + 1] = hp.y;
            }
            gates8<20, 20>(wih1r, whh1r, bs1, xin2, h1in, u0, a8);
            float2 h1p = cell_update(a8, cc);
            lds.h1x[p][wu][lane] = h1p;
            if (wu == NW - 1) {                   // owns unit 9 = output channel
                float m  = lds.msk[t][lane] ? 1.0f : 0.0f;
                float ip = fmaxf(h1p.y * m, 0.0f);
                out[BB + (b0 + lane) * TT + t] = ip;
                tot += ip;
            }
            __syncthreads();
        }
        if (wu == NW - 1) out[b0 + lane] = tot;
    }
}

extern "C" void kernel_launch(void* const* d_in, const int* in_sizes, int n_in,
                              void* d_out, int out_size, void* d_ws, size_t ws_size,
                              hipStream_t stream) {
    const int*   e     = (const int*)  d_in[0];
    const float* f     = (const float*)d_in[1];
    const float* emb   = (const float*)d_in[2];
    const float* fw    = (const float*)d_in[3];
    const float* fb    = (const float*)d_in[4];
    const float* wih0  = (const float*)d_in[5];
    const float* whh0  = (const float*)d_in[6];
    const float* bih0  = (const float*)d_in[7];
    const float* bhh0  = (const float*)d_in[8];
    const float* wih0r = (const float*)d_in[9];
    const float* whh0r = (const float*)d_in[10];
    const float* bih0r = (const float*)d_in[11];
    const float* bhh0r = (const float*)d_in[12];
    // d_in[13..16] = layer-1 forward weights: dead (output uses only bwd unit 9)
    const float* wih1r = (const float*)d_in[17];
    const float* whh1r = (const float*)d_in[18];
    const float* bih1r = (const float*)d_in[19];
    const float* bhh1r = (const float*)d_in[20];
    float* out = (float*)d_out;

    const size_t need = (size_t)NBLK * TT * NW * EPB * 4;  // 26.2 MB hf0 staging
    dim3 grid(NBLK), block(NW * 64);
    if (ws_size >= need) {
        hipLaunchKernelGGL(bilstm_unit_split<true>, grid, block, 0, stream,
                           e, f, emb, fw, fb, wih0, whh0, bih0, bhh0,
                           wih0r, whh0r, bih0r, bhh0r, wih1r, whh1r, bih1r, bhh1r,
                           (unsigned*)d_ws, out);
    } else {
        hipLaunchKernelGGL(bilstm_unit_split<false>, grid, block, 0, stream,
                           e, f, emb, fw, fb, wih0, whh0, bih0, bhh0,
                           wih0r, whh0r, bih0r, bhh0r, wih1r, whh1r, bih1r, bhh1r,
                           (unsigned*)nullptr, out);
    }
}

// Round 5
// 172.287 us; speedup vs baseline: 1.7955x; 1.7955x over previous
//
#include <hip/hip_runtime.h>

#define BB 65536
#define TT 20
#define HH 10
#define EPB 64
#define NW  5                 // waves/block; wave w owns units {2w, 2w+1}
#define NBLK (BB / EPB)       // 1024 blocks

// d_ws layout (u32 units)
#define WS_W0F 0              // layer0 fwd:  40 rows x 8 packed-f16-pair u32
#define WS_W0B 320            // layer0 bwd:  40 x 8
#define WS_W1  640            // layer1 bwd:  40 x 16 (15 + zero pad)
#define WS_B0F 1280           // fused biases (f32 bits): 40 each
#define WS_B0B 1320
#define WS_B1  1360
#define WS_HF0 2048           // hf0 staging: NBLK*TT*NW*EPB u32 (26.2 MB)

typedef __fp16 h2v __attribute__((ext_vector_type(2)));

__device__ __forceinline__ float sigmoid_f(float x) {
    float t = __builtin_amdgcn_exp2f(-1.44269504f * x);   // e^-x
    return __builtin_amdgcn_rcpf(1.0f + t);
}
__device__ __forceinline__ float tanh_f(float x) {
    float t = __builtin_amdgcn_exp2f(2.88539008f * x);    // e^(2x)
    return 1.0f - 2.0f * __builtin_amdgcn_rcpf(t + 1.0f);
}
__device__ __forceinline__ unsigned pk_h16(float a, float b) {
    h2v v = __builtin_amdgcn_cvt_pkrtz(a, b);
    return __builtin_bit_cast(unsigned, v);
}
__device__ __forceinline__ float dot2(unsigned w, unsigned x, float acc) {
#if __has_builtin(__builtin_amdgcn_fdot2)
    return __builtin_amdgcn_fdot2(__builtin_bit_cast(h2v, w),
                                  __builtin_bit_cast(h2v, x), acc, false);
#else
    h2v wv = __builtin_bit_cast(h2v, w), xv = __builtin_bit_cast(h2v, x);
    return fmaf((float)wv[0], (float)xv[0], fmaf((float)wv[1], (float)xv[1], acc));
#endif
}

// a8 order: ri = gate*2 + subunit -> i:0,1  f:2,3  g:4,5  o:6,7
__device__ __forceinline__ float2 cell_update(const float* a8, float* c0, float* c1) {
    float i0 = sigmoid_f(a8[0]), f0 = sigmoid_f(a8[2]);
    float g0 = tanh_f(a8[4]),    o0 = sigmoid_f(a8[6]);
    *c0 = fmaf(f0, *c0, i0 * g0);
    float h0 = o0 * tanh_f(*c0);
    float i1 = sigmoid_f(a8[1]), f1 = sigmoid_f(a8[3]);
    float g1 = tanh_f(a8[5]),    o1 = sigmoid_f(a8[7]);
    *c1 = fmaf(f1, *c1, i1 * g1);
    float h1 = o1 * tanh_f(*c1);
    return make_float2(h0, h1);
}

// ---------------- prep: pack weights to f16 pairs in d_ws ----------------
__global__ __launch_bounds__(256)
void prep_pack(
    const float* __restrict__ wih0, const float* __restrict__ whh0,
    const float* __restrict__ bih0, const float* __restrict__ bhh0,
    const float* __restrict__ wih0r,const float* __restrict__ whh0r,
    const float* __restrict__ bih0r,const float* __restrict__ bhh0r,
    const float* __restrict__ wih1r,const float* __restrict__ whh1r,
    const float* __restrict__ bih1r,const float* __restrict__ bhh1r,
    unsigned* __restrict__ ws)
{
    int tid = threadIdx.x;
    for (int i = tid; i < 320; i += 256) {      // layer-0 fwd + bwd rows
        int row = i >> 3, k = i & 7;
        float a, b;
        if (k < 3) { a = wih0[row * 6 + 2 * k];        b = wih0[row * 6 + 2 * k + 1]; }
        else       { a = whh0[row * 10 + 2 * (k - 3)]; b = whh0[row * 10 + 2 * (k - 3) + 1]; }
        ws[WS_W0F + i] = pk_h16(a, b);
        if (k < 3) { a = wih0r[row * 6 + 2 * k];        b = wih0r[row * 6 + 2 * k + 1]; }
        else       { a = whh0r[row * 10 + 2 * (k - 3)]; b = whh0r[row * 10 + 2 * (k - 3) + 1]; }
        ws[WS_W0B + i] = pk_h16(a, b);
    }
    for (int i = tid; i < 640; i += 256) {      // layer-1 bwd rows (K=30 -> 15 pairs + pad)
        int row = i >> 4, k = i & 15;
        float a = 0.f, b = 0.f;
        if (k < 10)      { a = wih1r[row * 20 + 2 * k];         b = wih1r[row * 20 + 2 * k + 1]; }
        else if (k < 15) { a = whh1r[row * 10 + 2 * (k - 10)];  b = whh1r[row * 10 + 2 * (k - 10) + 1]; }
        ws[WS_W1 + i] = pk_h16(a, b);
    }
    for (int i = tid; i < 40; i += 256) {       // fused biases (f32)
        ws[WS_B0F + i] = __float_as_uint(bih0[i]  + bhh0[i]);
        ws[WS_B0B + i] = __float_as_uint(bih0r[i] + bhh0r[i]);
        ws[WS_B1  + i] = __float_as_uint(bih1r[i] + bhh1r[i]);
    }
}

template<bool WS> struct LdsBuf {
    unsigned      x6[TT][3][EPB];              // 15360  x (6ch) f16 pairs
    unsigned      hbx[2][NW][EPB];             //  2560  h exchange (f16 pairs), dbuf
    unsigned      h1x[2][NW][EPB];             //  2560  h1 exchange, dbuf
    unsigned char msk[TT][EPB];                //  1280
    unsigned      hf0[WS ? 1 : TT][NW][EPB];   // fallback-only hf0
};  // WS=true: 21760 B ; WS=false: 47360 B

template<bool WS>
__global__ __launch_bounds__(NW * 64, 6)
void bilstm_dot2(
    const int*   __restrict__ e,   const float* __restrict__ f,
    const float* __restrict__ emb, const float* __restrict__ fw,
    const float* __restrict__ fb,
    const unsigned* __restrict__ wsr,   // packed weights (read-only region)
    unsigned* __restrict__ gws,         // hf0 staging region (WS=true)
    float* __restrict__ out)
{
    __shared__ LdsBuf<WS> lds;
    const int tid  = threadIdx.x;
    const int lane = tid & 63;
    const int wu   = __builtin_amdgcn_readfirstlane(tid >> 6);
    const int bid  = blockIdx.x;
    const int b0   = bid * EPB;
    const int u0   = 2 * wu;

    // ---------------- Stage x (coalesced global reads) ----------------
    {
        float fw0=fw[0],fw1=fw[1],fw2=fw[2],fw3=fw[3],fw4=fw[4];
        float fw5=fw[5],fw6=fw[6],fw7=fw[7],fw8=fw[8];
        float fb0=fb[0],fb1=fb[1],fb2=fb[2];
#pragma unroll
        for (int it = 0; it < (EPB * TT) / (NW * 64); ++it) {
            int p = tid + it * NW * 64;          // p = elem*TT + t
            int elem = p / TT, t = p - elem * TT;
            float f0  = f[b0 * TT * 3 + p * 3 + 0];
            float f1  = f[b0 * TT * 3 + p * 3 + 1];
            float f2v = f[b0 * TT * 3 + p * 3 + 2];
            int   ei  = e[b0 * TT + p] * 3;
            float x0 = emb[ei], x1 = emb[ei + 1], x2 = emb[ei + 2];
            float x3 = fmaf(fw0, f0, fmaf(fw1, f1, fmaf(fw2, f2v, fb0)));
            float x4 = fmaf(fw3, f0, fmaf(fw4, f1, fmaf(fw5, f2v, fb1)));
            float x5 = fmaf(fw6, f0, fmaf(fw7, f1, fmaf(fw8, f2v, fb2)));
            lds.x6[t][0][elem] = pk_h16(x0, x1);
            lds.x6[t][1][elem] = pk_h16(x2, x3);
            lds.x6[t][2][elem] = pk_h16(x4, x5);
            lds.msk[t][elem]   = (f1 != 0.0f) ? 1 : 0;
        }
        lds.hbx[1][wu][lane] = 0u;   // h(-1)=0 (t=0 reads parity 1)
        lds.h1x[0][wu][lane] = 0u;   // h1(20)=0 (t=19 reads parity 0)
    }
    __syncthreads();

    // ---------------- Phase 1: layer-0 forward (1 barrier/t) ----------------
    {
        unsigned wA[8][8]; float bA[8];
#pragma unroll
        for (int q = 0; q < 4; ++q)
#pragma unroll
            for (int s = 0; s < 2; ++s) {
                const int r = q * HH + u0 + s, ri = q * 2 + s;   // wave-uniform
                bA[ri] = __uint_as_float(wsr[WS_B0F + r]);
#pragma unroll
                for (int k = 0; k < 8; ++k) wA[ri][k] = wsr[WS_W0F + r * 8 + k];
            }
        float c0 = 0.f, c1 = 0.f;
#pragma unroll 1
        for (int t = 0; t < TT; ++t) {
            const int p = t & 1;
            unsigned xu[3], hu[NW];
#pragma unroll
            for (int j = 0; j < 3; ++j) xu[j] = lds.x6[t][j][lane];
#pragma unroll
            for (int j = 0; j < NW; ++j) hu[j] = lds.hbx[p ^ 1][j][lane];
            float a8[8];
#pragma unroll
            for (int ri = 0; ri < 8; ++ri) {
                float acc = bA[ri];
#pragma unroll
                for (int k = 0; k < 3; ++k) acc = dot2(wA[ri][k], xu[k], acc);
#pragma unroll
                for (int k = 0; k < NW; ++k) acc = dot2(wA[ri][3 + k], hu[k], acc);
                a8[ri] = acc;
            }
            float2 hp = cell_update(a8, &c0, &c1);
            unsigned hpu = pk_h16(hp.x, hp.y);
            lds.hbx[p][wu][lane] = hpu;
            if (WS) gws[((bid * TT + t) * NW + wu) * EPB + lane] = hpu;
            else    lds.hf0[t][wu][lane] = hpu;
            __syncthreads();
        }
    }
    lds.hbx[0][wu][lane] = 0u;       // hb(20)=0 for phase 2 (t=19 reads parity 0)
    __syncthreads();

    // ---- Phase 2: fused layer-0 bwd + layer-1 bwd (1 barrier/t, dbuf-proven) ----
    {
        unsigned wAb[8][8]; float bAb[8], bB[8];
#pragma unroll
        for (int q = 0; q < 4; ++q)
#pragma unroll
            for (int s = 0; s < 2; ++s) {
                const int r = q * HH + u0 + s, ri = q * 2 + s;
                bAb[ri] = __uint_as_float(wsr[WS_B0B + r]);
                bB[ri]  = __uint_as_float(wsr[WS_B1 + r]);
#pragma unroll
                for (int k = 0; k < 8; ++k) wAb[ri][k] = wsr[WS_W0B + r * 8 + k];
            }
        float cb0 = 0.f, cb1 = 0.f, cc0 = 0.f, cc1 = 0.f, tot = 0.f;
#pragma unroll 1
        for (int t = TT - 1; t >= 0; --t) {
            const int p = t & 1, pq = p ^ 1;
            unsigned hfu[NW];
            if (WS) {   // prefetch hf0[t]; consumed in cellB (vmcnt-hidden under cellA)
#pragma unroll
                for (int j = 0; j < NW; ++j)
                    hfu[j] = gws[((bid * TT + t) * NW + j) * EPB + lane];
            }
            // ---- cellA: layer-0 backward ----
            unsigned xu[3], hu[NW];
#pragma unroll
            for (int j = 0; j < 3; ++j) xu[j] = lds.x6[t][j][lane];
#pragma unroll
            for (int j = 0; j < NW; ++j) hu[j] = lds.hbx[pq][j][lane];
            float a8[8];
#pragma unroll
            for (int ri = 0; ri < 8; ++ri) {
                float acc = bAb[ri];
#pragma unroll
                for (int k = 0; k < 3; ++k) acc = dot2(wAb[ri][k], xu[k], acc);
#pragma unroll
                for (int k = 0; k < NW; ++k) acc = dot2(wAb[ri][3 + k], hu[k], acc);
                a8[ri] = acc;
            }
            float2 hbp = cell_update(a8, &cb0, &cb1);
            lds.hbx[p][wu][lane] = pk_h16(hbp.x, hbp.y);
            __syncthreads();

            // ---- cellB: layer-1 backward, input pairs = [hf0(5) | hb(5) | h1(5)] ----
            if (!WS) {
#pragma unroll
                for (int j = 0; j < NW; ++j) hfu[j] = lds.hf0[t][j][lane];
            }
            unsigned hb_[NW], h1_[NW];
#pragma unroll
            for (int j = 0; j < NW; ++j) {
                hb_[j] = lds.hbx[p][j][lane];
                h1_[j] = lds.h1x[pq][j][lane];
            }
            float a8b[8];
#pragma unroll
            for (int ri = 0; ri < 8; ++ri) {
                const int r = (ri >> 1) * HH + u0 + (ri & 1);    // wave-uniform
                unsigned wB[16];
#pragma unroll
                for (int k = 0; k < 16; ++k) wB[k] = wsr[WS_W1 + r * 16 + k];
                float acc = bB[ri];
#pragma unroll
                for (int k = 0; k < NW; ++k) acc = dot2(wB[k],      hfu[k], acc);
#pragma unroll
                for (int k = 0; k < NW; ++k) acc = dot2(wB[5 + k],  hb_[k], acc);
#pragma unroll
                for (int k = 0; k < NW; ++k) acc = dot2(wB[10 + k], h1_[k], acc);
                a8b[ri] = acc;
            }
            float2 h1p = cell_update(a8b, &cc0, &cc1);
            lds.h1x[p][wu][lane] = pk_h16(h1p.x, h1p.y);
            if (wu == NW - 1) {                  // owns unit 9 = output channel
                float m  = lds.msk[t][lane] ? 1.0f : 0.0f;
                float ip = fmaxf(h1p.y * m, 0.0f);
                out[BB + (b0 + lane) * TT + t] = ip;
                tot += ip;
            }
            // no second barrier: hbx/h1x double-buffers make next-t writes disjoint
        }
        if (wu == NW - 1) out[b0 + lane] = tot;
    }
}

extern "C" void kernel_launch(void* const* d_in, const int* in_sizes, int n_in,
                              void* d_out, int out_size, void* d_ws, size_t ws_size,
                              hipStream_t stream) {
    const int*   e     = (const int*)  d_in[0];
    const float* f     = (const float*)d_in[1];
    const float* emb   = (const float*)d_in[2];
    const float* fw    = (const float*)d_in[3];
    const float* fb    = (const float*)d_in[4];
    const float* wih0  = (const float*)d_in[5];
    const float* whh0  = (const float*)d_in[6];
    const float* bih0  = (const float*)d_in[7];
    const float* bhh0  = (const float*)d_in[8];
    const float* wih0r = (const float*)d_in[9];
    const float* whh0r = (const float*)d_in[10];
    const float* bih0r = (const float*)d_in[11];
    const float* bhh0r = (const float*)d_in[12];
    // d_in[13..16] = layer-1 forward weights: dead (output uses only bwd unit 9)
    const float* wih1r = (const float*)d_in[17];
    const float* whh1r = (const float*)d_in[18];
    const float* bih1r = (const float*)d_in[19];
    const float* bhh1r = (const float*)d_in[20];
    float* out = (float*)d_out;
    unsigned* ws = (unsigned*)d_ws;

    hipLaunchKernelGGL(prep_pack, dim3(1), dim3(256), 0, stream,
                       wih0, whh0, bih0, bhh0, wih0r, whh0r, bih0r, bhh0r,
                       wih1r, whh1r, bih1r, bhh1r, ws);

    const size_t need = (size_t)(WS_HF0 + (size_t)NBLK * TT * NW * EPB) * 4;
    dim3 grid(NBLK), block(NW * 64);
    if (ws_size >= need) {
        hipLaunchKernelGGL(bilstm_dot2<true>, grid, block, 0, stream,
                           e, f, emb, fw, fb, ws, ws + WS_HF0, out);
    } else {
        hipLaunchKernelGGL(bilstm_dot2<false>, grid, block, 0, stream,
                           e, f, emb, fw, fb, ws, ws + WS_HF0, out);
    }
}

// Round 7
// 132.662 us; speedup vs baseline: 2.3318x; 1.2987x over previous
//
#include <hip/hip_runtime.h>

#define BB 65536
#define TT 20
#define HH 10
#define EPB 64
#define NW  5                 // waves/block; wave w owns units {2w, 2w+1}
#define NBLK (BB / EPB)       // 1024 blocks

// d_ws layout (u32 units)
#define WS_W0F 0              // layer0 fwd:  40 rows x 8 packed-f16-pair u32
#define WS_W0B 320            // layer0 bwd:  40 x 8
#define WS_W1  640            // layer1 bwd:  40 x 16 (15 + zero pad)
#define WS_B0F 1280           // fused biases (f32 bits): 40 each
#define WS_B0B 1320
#define WS_B1  1360
#define WS_HF0 2048           // hf0 staging: NBLK*TT*NW*EPB u32 (26.2 MB)

#define LOG2E  1.442695041f
#define LOG2E2 2.885390082f

typedef __fp16 h2v __attribute__((ext_vector_type(2)));

__device__ __forceinline__ float sigmoid_f(float x) {
    float t = __builtin_amdgcn_exp2f(-LOG2E * x);   // e^-x
    return __builtin_amdgcn_rcpf(1.0f + t);
}
__device__ __forceinline__ float tanh_f(float x) {
    float t = __builtin_amdgcn_exp2f(LOG2E2 * x);   // e^(2x)
    return 1.0f - 2.0f * __builtin_amdgcn_rcpf(t + 1.0f);
}
__device__ __forceinline__ unsigned pk_h16(float a, float b) {
    h2v v = __builtin_amdgcn_cvt_pkrtz(a, b);
    return __builtin_bit_cast(unsigned, v);
}
// Single-instruction packed dot: acc += w.lo*x.lo + w.hi*x.hi (f32 accumulate).
// Weight constrained to SGPR (wave-uniform; VOP3P allows 1 scalar source) so
// the 64-entry weight working sets cost ZERO VGPRs.
__device__ __forceinline__ float dot2(unsigned w, unsigned x, float acc) {
    float r;
    asm("v_dot2_f32_f16 %0, %1, %2, %3" : "=v"(r) : "s"(w), "v"(x), "v"(acc));
    return r;
}

// a8 order: ri = gate*2 + subunit -> i:0,1  f:2,3  g:4,5  o:6,7
__device__ __forceinline__ float2 cell_update(const float* a8, float* c0, float* c1) {
    float i0 = sigmoid_f(a8[0]), f0 = sigmoid_f(a8[2]);
    float g0 = tanh_f(a8[4]),    o0 = sigmoid_f(a8[6]);
    *c0 = fmaf(f0, *c0, i0 * g0);
    float h0 = o0 * tanh_f(*c0);
    float i1 = sigmoid_f(a8[1]), f1 = sigmoid_f(a8[3]);
    float g1 = tanh_f(a8[5]),    o1 = sigmoid_f(a8[7]);
    *c1 = fmaf(f1, *c1, i1 * g1);
    float h1 = o1 * tanh_f(*c1);
    return make_float2(h0, h1);
}

// ---------------- prep: pack weights (UNSCALED) to f16 pairs in d_ws ----------------
__global__ __launch_bounds__(256)
void prep_pack(
    const float* __restrict__ wih0, const float* __restrict__ whh0,
    const float* __restrict__ bih0, const float* __restrict__ bhh0,
    const float* __restrict__ wih0r,const float* __restrict__ whh0r,
    const float* __restrict__ bih0r,const float* __restrict__ bhh0r,
    const float* __restrict__ wih1r,const float* __restrict__ whh1r,
    const float* __restrict__ bih1r,const float* __restrict__ bhh1r,
    unsigned* __restrict__ ws)
{
    int tid = threadIdx.x;
    for (int i = tid; i < 320; i += 256) {      // layer-0 fwd + bwd rows
        int row = i >> 3, k = i & 7;
        float a, b;
        if (k < 3) { a = wih0[row * 6 + 2 * k];        b = wih0[row * 6 + 2 * k + 1]; }
        else       { a = whh0[row * 10 + 2 * (k - 3)]; b = whh0[row * 10 + 2 * (k - 3) + 1]; }
        ws[WS_W0F + i] = pk_h16(a, b);
        if (k < 3) { a = wih0r[row * 6 + 2 * k];        b = wih0r[row * 6 + 2 * k + 1]; }
        else       { a = whh0r[row * 10 + 2 * (k - 3)]; b = whh0r[row * 10 + 2 * (k - 3) + 1]; }
        ws[WS_W0B + i] = pk_h16(a, b);
    }
    for (int i = tid; i < 640; i += 256) {      // layer-1 bwd rows (K=30 -> 15 pairs + pad)
        int row = i >> 4, k = i & 15;
        float a = 0.f, b = 0.f;
        if (k < 10)      { a = wih1r[row * 20 + 2 * k];         b = wih1r[row * 20 + 2 * k + 1]; }
        else if (k < 15) { a = whh1r[row * 10 + 2 * (k - 10)];  b = whh1r[row * 10 + 2 * (k - 10) + 1]; }
        ws[WS_W1 + i] = pk_h16(a, b);
    }
    for (int i = tid; i < 40; i += 256) {       // fused biases (f32)
        ws[WS_B0F + i] = __float_as_uint(bih0[i]  + bhh0[i]);
        ws[WS_B0B + i] = __float_as_uint(bih0r[i] + bhh0r[i]);
        ws[WS_B1  + i] = __float_as_uint(bih1r[i] + bhh1r[i]);
    }
}

template<bool WS> struct LdsBuf {
    unsigned      x6[TT][3][EPB];              // 15360  x (6ch) f16 pairs
    unsigned      hbx[2][NW][EPB];             //  2560  h exchange (f16 pairs), dbuf
    unsigned      h1x[2][NW][EPB];             //  2560  h1 exchange, dbuf
    unsigned char msk[TT][EPB];                //  1280
    unsigned      hf0[WS ? 1 : TT][NW][EPB];   // fallback-only hf0
};

template<bool WS>
__global__ __launch_bounds__(NW * 64, 6)
void bilstm_dot2(
    const int*   __restrict__ e,   const float* __restrict__ f,
    const float* __restrict__ emb, const float* __restrict__ fw,
    const float* __restrict__ fb,
    const unsigned* __restrict__ wsr,   // packed weights (read-only region)
    unsigned* __restrict__ gws,         // hf0 staging region (WS=true)
    float* __restrict__ out)
{
    __shared__ LdsBuf<WS> lds;
    const int tid  = threadIdx.x;
    const int lane = tid & 63;
    const int wu   = __builtin_amdgcn_readfirstlane(tid >> 6);
    const int bid  = blockIdx.x;
    const int b0   = bid * EPB;
    const int u0   = 2 * wu;

    // ---------------- Stage x (coalesced global reads) ----------------
    {
        float fw0=fw[0],fw1=fw[1],fw2=fw[2],fw3=fw[3],fw4=fw[4];
        float fw5=fw[5],fw6=fw[6],fw7=fw[7],fw8=fw[8];
        float fb0=fb[0],fb1=fb[1],fb2=fb[2];
#pragma unroll
        for (int it = 0; it < (EPB * TT) / (NW * 64); ++it) {
            int p = tid + it * NW * 64;          // p = elem*TT + t
            int elem = p / TT, t = p - elem * TT;
            float f0  = f[b0 * TT * 3 + p * 3 + 0];
            float f1  = f[b0 * TT * 3 + p * 3 + 1];
            float f2v = f[b0 * TT * 3 + p * 3 + 2];
            int   ei  = e[b0 * TT + p] * 3;
            float x0 = emb[ei], x1 = emb[ei + 1], x2 = emb[ei + 2];
            float x3 = fmaf(fw0, f0, fmaf(fw1, f1, fmaf(fw2, f2v, fb0)));
            float x4 = fmaf(fw3, f0, fmaf(fw4, f1, fmaf(fw5, f2v, fb1)));
            float x5 = fmaf(fw6, f0, fmaf(fw7, f1, fmaf(fw8, f2v, fb2)));
            lds.x6[t][0][elem] = pk_h16(x0, x1);
            lds.x6[t][1][elem] = pk_h16(x2, x3);
            lds.x6[t][2][elem] = pk_h16(x4, x5);
            lds.msk[t][elem]   = (f1 != 0.0f) ? 1 : 0;
        }
        lds.hbx[1][wu][lane] = 0u;   // h(-1)=0 (t=0 reads parity 1)
        lds.h1x[0][wu][lane] = 0u;   // h1(20)=0 (t=19 reads parity 0)
    }
    __syncthreads();

    // ---------------- Phase 1: layer-0 forward (1 barrier/t) ----------------
    {
        unsigned wA[8][8]; float bA[8];
#pragma unroll
        for (int q = 0; q < 4; ++q)
#pragma unroll
            for (int s = 0; s < 2; ++s) {
                const int r = q * HH + u0 + s, ri = q * 2 + s;   // wave-uniform
                bA[ri] = __uint_as_float(wsr[WS_B0F + r]);
#pragma unroll
                for (int k = 0; k < 8; ++k) wA[ri][k] = wsr[WS_W0F + r * 8 + k];
            }
        float c0 = 0.f, c1 = 0.f;
#pragma unroll 1
        for (int t = 0; t < TT; ++t) {
            const int p = t & 1;
            unsigned xu[3], hu[NW];
#pragma unroll
            for (int j = 0; j < 3; ++j) xu[j] = lds.x6[t][j][lane];
#pragma unroll
            for (int j = 0; j < NW; ++j) hu[j] = lds.hbx[p ^ 1][j][lane];
            float a8[8];
#pragma unroll
            for (int ri = 0; ri < 8; ++ri) {
                float acc = bA[ri];
#pragma unroll
                for (int k = 0; k < 3; ++k) acc = dot2(wA[ri][k], xu[k], acc);
#pragma unroll
                for (int k = 0; k < NW; ++k) acc = dot2(wA[ri][3 + k], hu[k], acc);
                a8[ri] = acc;
            }
            float2 hp = cell_update(a8, &c0, &c1);
            unsigned hpu = pk_h16(hp.x, hp.y);
            lds.hbx[p][wu][lane] = hpu;
            if (WS) gws[((bid * TT + t) * NW + wu) * EPB + lane] = hpu;
            else    lds.hf0[t][wu][lane] = hpu;
            __syncthreads();
        }
    }
    lds.hbx[0][wu][lane] = 0u;       // hb(20)=0 for phase 2 (t=19 reads parity 0)
    __syncthreads();

    // ---- Phase 2: fused layer-0 bwd + layer-1 bwd (1 barrier/t) ----
    {
        unsigned wAb[8][8]; float bAb[8], bB[8];
#pragma unroll
        for (int q = 0; q < 4; ++q)
#pragma unroll
            for (int s = 0; s < 2; ++s) {
                const int r = q * HH + u0 + s, ri = q * 2 + s;
                bAb[ri] = __uint_as_float(wsr[WS_B0B + r]);
                bB[ri]  = __uint_as_float(wsr[WS_B1 + r]);
#pragma unroll
                for (int k = 0; k < 8; ++k) wAb[ri][k] = wsr[WS_W0B + r * 8 + k];
            }
        float cb0 = 0.f, cb1 = 0.f, cc0 = 0.f, cc1 = 0.f, tot = 0.f;
#pragma unroll 1
        for (int t = TT - 1; t >= 0; --t) {
            const int p = t & 1, pq = p ^ 1;
            unsigned hfu[NW];
            if (WS) {   // prefetch hf0[t]; consumed in cellB (latency hidden under cellA)
#pragma unroll
                for (int j = 0; j < NW; ++j)
                    hfu[j] = gws[((bid * TT + t) * NW + j) * EPB + lane];
            }
            // ---- cellA: layer-0 backward ----
            unsigned xu[3], hu[NW];
#pragma unroll
            for (int j = 0; j < 3; ++j) xu[j] = lds.x6[t][j][lane];
#pragma unroll
            for (int j = 0; j < NW; ++j) hu[j] = lds.hbx[pq][j][lane];
            float a8[8];
#pragma unroll
            for (int ri = 0; ri < 8; ++ri) {
                float acc = bAb[ri];
#pragma unroll
                for (int k = 0; k < 3; ++k) acc = dot2(wAb[ri][k], xu[k], acc);
#pragma unroll
                for (int k = 0; k < NW; ++k) acc = dot2(wAb[ri][3 + k], hu[k], acc);
                a8[ri] = acc;
            }
            float2 hbp = cell_update(a8, &cb0, &cb1);
            lds.hbx[p][wu][lane] = pk_h16(hbp.x, hbp.y);
            __syncthreads();

            // ---- cellB: layer-1 backward; row weights software-pipelined 1-deep ----
            if (!WS) {
#pragma unroll
                for (int j = 0; j < NW; ++j) hfu[j] = lds.hf0[t][j][lane];
            }
            unsigned hb_[NW], h1_[NW];
#pragma unroll
            for (int j = 0; j < NW; ++j) {
                hb_[j] = lds.hbx[p][j][lane];
                h1_[j] = lds.h1x[pq][j][lane];
            }
            float a8b[8];
            unsigned wBc[16];
            {
                const int r0 = u0;               // ri=0 row
#pragma unroll
                for (int k = 0; k < 16; ++k) wBc[k] = wsr[WS_W1 + r0 * 16 + k];
            }
#pragma unroll
            for (int ri = 0; ri < 8; ++ri) {
                unsigned wBn[16];
                if (ri < 7) {
                    const int rn = ((ri + 1) >> 1) * HH + u0 + ((ri + 1) & 1);
#pragma unroll
                    for (int k = 0; k < 16; ++k) wBn[k] = wsr[WS_W1 + rn * 16 + k];
                }
                float acc = bB[ri];
#pragma unroll
                for (int k = 0; k < NW; ++k) acc = dot2(wBc[k],      hfu[k], acc);
#pragma unroll
                for (int k = 0; k < NW; ++k) acc = dot2(wBc[5 + k],  hb_[k], acc);
#pragma unroll
                for (int k = 0; k < NW; ++k) acc = dot2(wBc[10 + k], h1_[k], acc);
                a8b[ri] = acc;
                if (ri < 7) {
#pragma unroll
                    for (int k = 0; k < 16; ++k) wBc[k] = wBn[k];
                }
            }
            float2 h1p = cell_update(a8b, &cc0, &cc1);
            lds.h1x[p][wu][lane] = pk_h16(h1p.x, h1p.y);
            if (wu == NW - 1) {                  // owns unit 9 = output channel
                float m  = lds.msk[t][lane] ? 1.0f : 0.0f;
                float ip = fmaxf(h1p.y * m, 0.0f);
                out[BB + (b0 + lane) * TT + t] = ip;
                tot += ip;
            }
            // no second barrier: hbx/h1x double-buffers make next-t writes disjoint
        }
        if (wu == NW - 1) out[b0 + lane] = tot;
    }
}

extern "C" void kernel_launch(void* const* d_in, const int* in_sizes, int n_in,
                              void* d_out, int out_size, void* d_ws, size_t ws_size,
                              hipStream_t stream) {
    const int*   e     = (const int*)  d_in[0];
    const float* f     = (const float*)d_in[1];
    const float* emb   = (const float*)d_in[2];
    const float* fw    = (const float*)d_in[3];
    const float* fb    = (const float*)d_in[4];
    const float* wih0  = (const float*)d_in[5];
    const float* whh0  = (const float*)d_in[6];
    const float* bih0  = (const float*)d_in[7];
    const float* bhh0  = (const float*)d_in[8];
    const float* wih0r = (const float*)d_in[9];
    const float* whh0r = (const float*)d_in[10];
    const float* bih0r = (const float*)d_in[11];
    const float* bhh0r = (const float*)d_in[12];
    // d_in[13..16] = layer-1 forward weights: dead (output uses only bwd unit 9)
    const float* wih1r = (const float*)d_in[17];
    const float* whh1r = (const float*)d_in[18];
    const float* bih1r = (const float*)d_in[19];
    const float* bhh1r = (const float*)d_in[20];
    float* out = (float*)d_out;
    unsigned* ws = (unsigned*)d_ws;

    hipLaunchKernelGGL(prep_pack, dim3(1), dim3(256), 0, stream,
                       wih0, whh0, bih0, bhh0, wih0r, whh0r, bih0r, bhh0r,
                       wih1r, whh1r, bih1r, bhh1r, ws);

    const size_t need = (size_t)(WS_HF0 + (size_t)NBLK * TT * NW * EPB) * 4;
    dim3 grid(NBLK), block(NW * 64);
    if (ws_size >= need) {
        hipLaunchKernelGGL(bilstm_dot2<true>, grid, block, 0, stream,
                           e, f, emb, fw, fb, ws, ws + WS_HF0, out);
    } else {
        hipLaunchKernelGGL(bilstm_dot2<false>, grid, block, 0, stream,
                           e, f, emb, fw, fb, ws, ws + WS_HF0, out);
    }
}

// Round 8
// 72.846 us; speedup vs baseline: 4.2465x; 1.8211x over previous
//
#include <hip/hip_runtime.h>

#define BB 65536
#define TT 20
#define NBLK 2048             // 1 wave / block, 32 elements / wave

#define WS_WGT 0              // 14 frags x 64 lanes x 4 u32 = 3584 u32
#define WS_HF0 4096           // hf0 B-frags: 2048*20*160 u32 = 26.2 MB
#define PK1 0x00003C00u       // f16 pair {1.0, 0.0}

#define LOG2E  1.442695041f
#define LOG2E2 2.885390082f

typedef unsigned u32;
typedef __fp16 f16x8 __attribute__((ext_vector_type(8)));
typedef float   f32x16 __attribute__((ext_vector_type(16)));
typedef u32     u32x4 __attribute__((ext_vector_type(4)));
typedef __fp16  h2v   __attribute__((ext_vector_type(2)));

__device__ __forceinline__ float sigmoid_f(float x) {
    float t = __builtin_amdgcn_exp2f(-LOG2E * x);
    return __builtin_amdgcn_rcpf(1.0f + t);
}
__device__ __forceinline__ float tanh_f(float x) {
    float t = __builtin_amdgcn_exp2f(LOG2E2 * x);
    return 1.0f - 2.0f * __builtin_amdgcn_rcpf(t + 1.0f);
}
__device__ __forceinline__ u32 pk_h16(float a, float b) {
    h2v v = __builtin_amdgcn_cvt_pkrtz(a, b);
    return __builtin_bit_cast(u32, v);
}
__device__ __forceinline__ f32x16 MFMA(u32x4 a, u32x4 b, f32x16 c) {
    return __builtin_amdgcn_mfma_f32_32x32x16_f16(
        __builtin_bit_cast(f16x8, a), __builtin_bit_cast(f16x8, b), c, 0, 0, 0);
}

// Assemble the h-input B-fragment (K layout [h0..h9, pad]); k = 4g+{0..3} U 8+4g+{0..3}.
// Lane-half g owns h_{5g+v} in h[v].  g0 needs {h01,h23,h89,-}; g1 needs {h45,h67,-,-}.
// One ds_bpermute crosses h4 (g0->g1) and pk(h8,h9) (g1->g0) simultaneously.
__device__ __forceinline__ u32x4 pack_h(const float* h, bool hi, int xaddr, u32 b3) {
    u32 send = hi ? pk_h16(h[3], h[4]) : __float_as_uint(h[4]);
    u32 recv = (u32)__builtin_amdgcn_ds_bpermute(xaddr, (int)send);
    u32 lo0 = pk_h16(h[0], h[1]), lo1 = pk_h16(h[2], h[3]);
    u32 hi0 = pk_h16(__uint_as_float(recv), h[0]);   // {h4, h5}
    u32 hi1 = pk_h16(h[1], h[2]);                    // {h6, h7}
    u32x4 b;
    b[0] = hi ? hi0 : lo0;
    b[1] = hi ? hi1 : lo1;
    b[2] = hi ? 0u : recv;                           // {h8, h9} on g0
    b[3] = b3;
    return b;
}

// C layout (verified): row = (r&3)+8*(r>>2)+4*(lane>>5).  With row-permutation
// pi(q, u=5h+v) = 8q+4h+v (v<4) | 32+4h+q (v=4), lane-half h's unit v gates are:
// v<4: i=a0[v], f=a0[4+v], g=a0[8+v], o=a0[12+v];  v=4: a1[0..3].
__device__ __forceinline__ void cell_update5(const f32x16 a0, const f32x16 a1,
                                             float* c, float* h) {
#pragma unroll
    for (int v = 0; v < 4; ++v) {
        float cv = fmaf(sigmoid_f(a0[4 + v]), c[v], sigmoid_f(a0[v]) * tanh_f(a0[8 + v]));
        c[v] = cv;
        h[v] = sigmoid_f(a0[12 + v]) * tanh_f(cv);
    }
    float cv = fmaf(sigmoid_f(a1[1]), c[4], sigmoid_f(a1[0]) * tanh_f(a1[2]));
    c[4] = cv;
    h[4] = sigmoid_f(a1[3]) * tanh_f(cv);
}

// ---------------- prep: build A-fragments (weights, permuted rows) ----------------
__device__ __forceinline__ int inv_pi(int row) {
    if (row < 32) { int q = row >> 3, rem = row & 7; return q * 10 + 5 * (rem >> 2) + (rem & 3); }
    if (row < 40) { int lo = row - 32; return (lo & 3) * 10 + 5 * (lo >> 2) + 4; }
    return -1;
}

__global__ __launch_bounds__(256)
void prep_mfma(
    const float* __restrict__ wih0, const float* __restrict__ whh0,
    const float* __restrict__ bih0, const float* __restrict__ bhh0,
    const float* __restrict__ wih0r,const float* __restrict__ whh0r,
    const float* __restrict__ bih0r,const float* __restrict__ bhh0r,
    const float* __restrict__ wih1r,const float* __restrict__ whh1r,
    const float* __restrict__ bih1r,const float* __restrict__ bhh1r,
    u32* __restrict__ ws)
{
    for (int gid = threadIdx.x; gid < 14 * 64 * 4; gid += 256) {
        int fid = gid >> 8, l = (gid >> 2) & 63, j = gid & 3;
        int g = l >> 5;
        int tile, chunk;
        if (fid < 8) { tile = (fid >> 1) & 1; chunk = fid & 1; }
        else         { int q = fid - 8; tile = q / 3; chunk = q % 3; }
        int row = tile * 32 + (l & 31);
        int orow = inv_pi(row);
        int kb = (j >> 1) * 8 + 4 * g + (j & 1) * 2;
        float v[2] = {0.f, 0.f};
        if (orow >= 0) {
#pragma unroll
            for (int s = 0; s < 2; ++s) {
                int k = kb + s;
                float val = 0.f;
                if (fid < 8) {
                    bool bwd = fid >= 4;
                    if (chunk == 0) {
                        if (k < 6)       val = (bwd ? wih0r : wih0)[orow * 6 + k];
                        else if (k == 6) val = (bwd ? bih0r[orow] + bhh0r[orow]
                                                    : bih0[orow] + bhh0[orow]);
                    } else {
                        if (k < 10)      val = (bwd ? whh0r : whh0)[orow * 10 + k];
                    }
                } else {
                    if (chunk == 0)      { if (k < 10) val = wih1r[orow * 20 + k]; }
                    else if (chunk == 1) { if (k < 10) val = wih1r[orow * 20 + 10 + k]; }
                    else {
                        if (k < 10)      val = whh1r[orow * 10 + k];
                        else if (k == 10) val = bih1r[orow] + bhh1r[orow];
                    }
                }
                v[s] = val;
            }
        }
        ws[WS_WGT + (fid * 64 + l) * 4 + j] = pk_h16(v[0], v[1]);
    }
}

// ---------------- main: wave-autonomous BiLSTM, zero barriers ----------------
template<bool WS> struct Lds {
    u32   x[TT][3][32];            // x pairs {x01,x23,x45} per (t, elem)
    float m[TT][32];               // mask
    u32   hf[WS ? 1 : TT][160];    // fallback hf0 frags
};

template<bool WS>
__global__ __launch_bounds__(64)
void bilstm_mfma(
    const int*   __restrict__ eidx, const float* __restrict__ f,
    const float* __restrict__ emb,  const float* __restrict__ fw,
    const float* __restrict__ fb,
    const u32* __restrict__ wsr, u32* __restrict__ ghf,
    float* __restrict__ out)
{
    __shared__ Lds<WS> lds;
    const int  lane = threadIdx.x;
    const int  e    = lane & 31;
    const bool hi   = lane >= 32;
    const int  wid  = blockIdx.x;
    const int  b0   = wid * 32;
    const int  xaddr = (lane ^ 32) << 2;
    u32* hfp = ghf + (size_t)wid * TT * 160;

    // ---- stage x into LDS (per-wave private; no barrier needed) ----
    {
        float fw0=fw[0],fw1=fw[1],fw2=fw[2],fw3=fw[3],fw4=fw[4];
        float fw5=fw[5],fw6=fw[6],fw7=fw[7],fw8=fw[8];
        float fb0=fb[0],fb1=fb[1],fb2=fb[2];
#pragma unroll 1
        for (int it = 0; it < 10; ++it) {
            int idx = lane + it * 64;            // 0..639
            int ee = idx / 20, t = idx - ee * 20;
            int gi = (b0 + ee) * TT + t;
            float f0 = f[gi * 3], f1 = f[gi * 3 + 1], f2v = f[gi * 3 + 2];
            int ei = eidx[gi] * 3;
            float x0 = emb[ei], x1 = emb[ei + 1], x2 = emb[ei + 2];
            float x3 = fmaf(fw0, f0, fmaf(fw1, f1, fmaf(fw2, f2v, fb0)));
            float x4 = fmaf(fw3, f0, fmaf(fw4, f1, fmaf(fw5, f2v, fb1)));
            float x5 = fmaf(fw6, f0, fmaf(fw7, f1, fmaf(fw8, f2v, fb2)));
            lds.x[t][0][ee] = pk_h16(x0, x1);
            lds.x[t][1][ee] = pk_h16(x2, x3);
            lds.x[t][2][ee] = pk_h16(x4, x5);
            lds.m[t][ee]    = (f1 != 0.f) ? 1.f : 0.f;
        }
    }

    const u32x4* wv = (const u32x4*)wsr;
    // ---- Phase 1: layer-0 forward ----
    {
        u32x4 wf0 = wv[0 * 64 + lane], wf1 = wv[1 * 64 + lane];
        u32x4 wf2 = wv[2 * 64 + lane], wf3 = wv[3 * 64 + lane];
        float cf[5] = {0,0,0,0,0}, hv[5] = {0,0,0,0,0};
#pragma unroll 1
        for (int t = 0; t < TT; ++t) {
            u32 x01 = lds.x[t][0][e], x23 = lds.x[t][1][e], x45 = lds.x[t][2][e];
            u32x4 bx; bx[0] = hi ? x45 : x01; bx[1] = hi ? PK1 : x23; bx[2] = 0u; bx[3] = 0u;
            u32x4 bh = pack_h(hv, hi, xaddr, 0u);
            f32x16 z = {};
            f32x16 a0 = MFMA(wf0, bx, z); a0 = MFMA(wf1, bh, a0);
            f32x16 a1 = MFMA(wf2, bx, z); a1 = MFMA(wf3, bh, a1);
            cell_update5(a0, a1, cf, hv);
            u32x4 st = pack_h(hv, hi, xaddr, 0u);
            if (WS) {
                *(uint2*)(hfp + t * 160 + lane * 2) = make_uint2(st[0], st[1]);
                if (!hi) hfp[t * 160 + 128 + e] = st[2];
            } else {
                lds.hf[t][lane * 2] = st[0]; lds.hf[t][lane * 2 + 1] = st[1];
                if (!hi) lds.hf[t][128 + e] = st[2];
            }
        }
    }

    // ---- Phase 2: fused layer-0 backward + layer-1 backward ----
    {
        u32x4 wb0 = wv[4 * 64 + lane], wb1 = wv[5 * 64 + lane];
        u32x4 wb2 = wv[6 * 64 + lane], wb3 = wv[7 * 64 + lane];
        u32x4 wB0 = wv[8 * 64 + lane], wB1 = wv[9 * 64 + lane], wB2 = wv[10 * 64 + lane];
        u32x4 wB3 = wv[11 * 64 + lane], wB4 = wv[12 * 64 + lane], wB5 = wv[13 * 64 + lane];
        float cb[5] = {0,0,0,0,0}, hbv[5] = {0,0,0,0,0};
        float cc[5] = {0,0,0,0,0}, h1v[5] = {0,0,0,0,0};
        float tot = 0.f;
#pragma unroll 1
        for (int t = TT - 1; t >= 0; --t) {
            uint2 ld2; u32 ldw;
            if (WS) { ld2 = *(const uint2*)(hfp + t * 160 + lane * 2);
                      ldw = hfp[t * 160 + 128 + e]; }
            else    { ld2 = make_uint2(lds.hf[t][lane * 2], lds.hf[t][lane * 2 + 1]);
                      ldw = lds.hf[t][128 + e]; }
            u32 x01 = lds.x[t][0][e], x23 = lds.x[t][1][e], x45 = lds.x[t][2][e];
            // cellA: layer-0 backward
            u32x4 bx; bx[0] = hi ? x45 : x01; bx[1] = hi ? PK1 : x23; bx[2] = 0u; bx[3] = 0u;
            u32x4 bh = pack_h(hbv, hi, xaddr, 0u);
            f32x16 z = {};
            f32x16 a0 = MFMA(wb0, bx, z); a0 = MFMA(wb1, bh, a0);
            f32x16 a1 = MFMA(wb2, bx, z); a1 = MFMA(wb3, bh, a1);
            cell_update5(a0, a1, cb, hbv);
            // cellB: layer-1 backward, K-chunks {hf0, hb, h1+bias}
            u32x4 bhf; bhf[0] = ld2.x; bhf[1] = ld2.y; bhf[2] = hi ? 0u : ldw; bhf[3] = 0u;
            u32x4 bhb = pack_h(hbv, hi, xaddr, 0u);
            u32x4 bh1 = pack_h(h1v, hi, xaddr, hi ? 0u : PK1);
            a0 = MFMA(wB0, bhf, z); a0 = MFMA(wB1, bhb, a0); a0 = MFMA(wB2, bh1, a0);
            a1 = MFMA(wB3, bhf, z); a1 = MFMA(wB4, bhb, a1); a1 = MFMA(wB5, bh1, a1);
            cell_update5(a0, a1, cc, h1v);
            if (hi) {                            // unit 9 = (half1, v=4)
                float ip = fmaxf(h1v[4] * lds.m[t][e], 0.f);
                out[BB + (b0 + e) * TT + t] = ip;
                tot += ip;
            }
        }
        if (hi) out[b0 + e] = tot;
    }
}

extern "C" void kernel_launch(void* const* d_in, const int* in_sizes, int n_in,
                              void* d_out, int out_size, void* d_ws, size_t ws_size,
                              hipStream_t stream) {
    const int*   eidx  = (const int*)  d_in[0];
    const float* f     = (const float*)d_in[1];
    const float* emb   = (const float*)d_in[2];
    const float* fw    = (const float*)d_in[3];
    const float* fb    = (const float*)d_in[4];
    const float* wih0  = (const float*)d_in[5];
    const float* whh0  = (const float*)d_in[6];
    const float* bih0  = (const float*)d_in[7];
    const float* bhh0  = (const float*)d_in[8];
    const float* wih0r = (const float*)d_in[9];
    const float* whh0r = (const float*)d_in[10];
    const float* bih0r = (const float*)d_in[11];
    const float* bhh0r = (const float*)d_in[12];
    // d_in[13..16] = layer-1 forward weights: dead (output uses only bwd unit 9)
    const float* wih1r = (const float*)d_in[17];
    const float* whh1r = (const float*)d_in[18];
    const float* bih1r = (const float*)d_in[19];
    const float* bhh1r = (const float*)d_in[20];
    float* out = (float*)d_out;
    u32* ws = (u32*)d_ws;

    hipLaunchKernelGGL(prep_mfma, dim3(1), dim3(256), 0, stream,
                       wih0, whh0, bih0, bhh0, wih0r, whh0r, bih0r, bhh0r,
                       wih1r, whh1r, bih1r, bhh1r, ws);

    const size_t need = (size_t)(WS_HF0 + (size_t)NBLK * TT * 160) * 4;
    dim3 grid(NBLK), block(64);
    if (ws_size >= need) {
        hipLaunchKernelGGL(bilstm_mfma<true>, grid, block, 0, stream,
                           eidx, f, emb, fw, fb, ws, ws + WS_HF0, out);
    } else {
        hipLaunchKernelGGL(bilstm_mfma<false>, grid, block, 0, stream,
                           eidx, f, emb, fw, fb, ws, ws + WS_HF0, out);
    }
}

// Round 9
// 69.939 us; speedup vs baseline: 4.4230x; 1.0416x over previous
//
#include <hip/hip_runtime.h>

#define BB 65536
#define TT 20
#define NBLK 2048             // 1 wave / block, 32 elements / wave

#define WS_WGT 0              // 14 frags x 64 lanes x 4 u32 = 3584 u32
#define WS_HF0 4096           // hf0 B-frags: 2048*20*160 u32 = 26.2 MB
#define PK1 0x00003C00u       // f16 pair {1.0, 0.0}

#define LOG2E  1.442695041f
#define LOG2E2 2.885390082f

typedef unsigned u32;
typedef __fp16 f16x8 __attribute__((ext_vector_type(8)));
typedef float   f32x16 __attribute__((ext_vector_type(16)));
typedef u32     u32x4 __attribute__((ext_vector_type(4)));
typedef __fp16  h2v   __attribute__((ext_vector_type(2)));

__device__ __forceinline__ u32 pk_h16(float a, float b) {
    h2v v = __builtin_amdgcn_cvt_pkrtz(a, b);
    return __builtin_bit_cast(u32, v);
}
__device__ __forceinline__ f32x16 MFMA(u32x4 a, u32x4 b, f32x16 c) {
    return __builtin_amdgcn_mfma_f32_32x32x16_f16(
        __builtin_bit_cast(f16x8, a), __builtin_bit_cast(f16x8, b), c, 0, 0, 0);
}

// Combined-rcp LSTM unit: sigma(i)*tanh(g) and sigma(o)*tanh(c) each share one
// rcp of the product of denominators. 8 trans ops/unit instead of 10.
__device__ __forceinline__ void unit_cr(float ai, float af, float ag, float ao,
                                        float* c, float* h) {
    float pi = __builtin_amdgcn_exp2f(-LOG2E * ai);
    float pf = __builtin_amdgcn_exp2f(-LOG2E * af);
    float q  = __builtin_amdgcn_exp2f(LOG2E2 * ag);
    float fv = __builtin_amdgcn_rcpf(1.0f + pf);
    float ig = (q - 1.0f) * __builtin_amdgcn_rcpf((1.0f + pi) * (q + 1.0f));
    float cv = fmaf(fv, *c, ig);
    *c = cv;
    float po = __builtin_amdgcn_exp2f(-LOG2E * ao);
    float qc = __builtin_amdgcn_exp2f(LOG2E2 * cv);
    *h = (qc - 1.0f) * __builtin_amdgcn_rcpf((1.0f + po) * (qc + 1.0f));
}

// Assemble the h-input B-fragment (K layout [h0..h9, pad]); k = 4g+{0..3} U 8+4g+{0..3}.
__device__ __forceinline__ u32x4 pack_h(const float* h, bool hi, int xaddr, u32 b3) {
    u32 send = hi ? pk_h16(h[3], h[4]) : __float_as_uint(h[4]);
    u32 recv = (u32)__builtin_amdgcn_ds_bpermute(xaddr, (int)send);
    u32 lo0 = pk_h16(h[0], h[1]), lo1 = pk_h16(h[2], h[3]);
    u32 hi0 = pk_h16(__uint_as_float(recv), h[0]);   // {h4, h5}
    u32 hi1 = pk_h16(h[1], h[2]);                    // {h6, h7}
    u32x4 b;
    b[0] = hi ? hi0 : lo0;
    b[1] = hi ? hi1 : lo1;
    b[2] = hi ? 0u : recv;                           // {h8, h9} on g0
    b[3] = b3;
    return b;
}

// C layout (verified): row = (r&3)+8*(r>>2)+4*(lane>>5).  Row-permutation
// pi(q, u=5h+v) = 8q+4h+v (v<4) | 32+4h+q (v=4).
__device__ __forceinline__ void cell_update5(const f32x16 a0, const f32x16 a1,
                                             float* c, float* h) {
#pragma unroll
    for (int v = 0; v < 4; ++v)
        unit_cr(a0[v], a0[4 + v], a0[8 + v], a0[12 + v], &c[v], &h[v]);
    unit_cr(a1[0], a1[1], a1[2], a1[3], &c[4], &h[4]);
}

// ---------------- prep: build A-fragments (weights, permuted rows) ----------------
__device__ __forceinline__ int inv_pi(int row) {
    if (row < 32) { int q = row >> 3, rem = row & 7; return q * 10 + 5 * (rem >> 2) + (rem & 3); }
    if (row < 40) { int lo = row - 32; return (lo & 3) * 10 + 5 * (lo >> 2) + 4; }
    return -1;
}

__global__ __launch_bounds__(256)
void prep_mfma(
    const float* __restrict__ wih0, const float* __restrict__ whh0,
    const float* __restrict__ bih0, const float* __restrict__ bhh0,
    const float* __restrict__ wih0r,const float* __restrict__ whh0r,
    const float* __restrict__ bih0r,const float* __restrict__ bhh0r,
    const float* __restrict__ wih1r,const float* __restrict__ whh1r,
    const float* __restrict__ bih1r,const float* __restrict__ bhh1r,
    u32* __restrict__ ws)
{
    for (int gid = threadIdx.x; gid < 14 * 64 * 4; gid += 256) {
        int fid = gid >> 8, l = (gid >> 2) & 63, j = gid & 3;
        int g = l >> 5;
        int tile, chunk;
        if (fid < 8) { tile = (fid >> 1) & 1; chunk = fid & 1; }
        else         { int q = fid - 8; tile = q / 3; chunk = q % 3; }
        int row = tile * 32 + (l & 31);
        int orow = inv_pi(row);
        int kb = (j >> 1) * 8 + 4 * g + (j & 1) * 2;
        float v[2] = {0.f, 0.f};
        if (orow >= 0) {
#pragma unroll
            for (int s = 0; s < 2; ++s) {
                int k = kb + s;
                float val = 0.f;
                if (fid < 8) {
                    bool bwd = fid >= 4;
                    if (chunk == 0) {
                        if (k < 6)       val = (bwd ? wih0r : wih0)[orow * 6 + k];
                        else if (k == 6) val = (bwd ? bih0r[orow] + bhh0r[orow]
                                                    : bih0[orow] + bhh0[orow]);
                    } else {
                        if (k < 10)      val = (bwd ? whh0r : whh0)[orow * 10 + k];
                    }
                } else {
                    if (chunk == 0)      { if (k < 10) val = wih1r[orow * 20 + k]; }
                    else if (chunk == 1) { if (k < 10) val = wih1r[orow * 20 + 10 + k]; }
                    else {
                        if (k < 10)      val = whh1r[orow * 10 + k];
                        else if (k == 10) val = bih1r[orow] + bhh1r[orow];
                    }
                }
                v[s] = val;
            }
        }
        ws[WS_WGT + (fid * 64 + l) * 4 + j] = pk_h16(v[0], v[1]);
    }
}

// ---------------- main: wave-autonomous BiLSTM, zero barriers ----------------
template<bool WS> struct Lds {
    u32   x[TT][3][32];            // x pairs {x01,x23,x45} per (t, elem)
    float m[TT][32];               // mask
    u32   hf[WS ? 1 : TT][160];    // fallback hf0 frags
};

template<bool WS>
__global__ __launch_bounds__(64)
void bilstm_mfma(
    const int*   __restrict__ eidx, const float* __restrict__ f,
    const float* __restrict__ emb,  const float* __restrict__ fw,
    const float* __restrict__ fb,
    const u32* __restrict__ wsr, u32* __restrict__ ghf,
    float* __restrict__ out)
{
    __shared__ Lds<WS> lds;
    const int  lane = threadIdx.x;
    const int  e    = lane & 31;
    const bool hi   = lane >= 32;
    const int  wid  = blockIdx.x;
    const int  b0   = wid * 32;
    const int  xaddr = (lane ^ 32) << 2;
    u32* hfp = ghf + (size_t)wid * TT * 160;

    // ---- stage x into LDS (per-wave private; no barrier needed) ----
    {
        float fw0=fw[0],fw1=fw[1],fw2=fw[2],fw3=fw[3],fw4=fw[4];
        float fw5=fw[5],fw6=fw[6],fw7=fw[7],fw8=fw[8];
        float fb0=fb[0],fb1=fb[1],fb2=fb[2];
#pragma unroll 1
        for (int it = 0; it < 10; ++it) {
            int idx = lane + it * 64;            // 0..639
            int ee = idx / 20, t = idx - ee * 20;
            int gi = (b0 + ee) * TT + t;
            float f0 = f[gi * 3], f1 = f[gi * 3 + 1], f2v = f[gi * 3 + 2];
            int ei = eidx[gi] * 3;
            float x0 = emb[ei], x1 = emb[ei + 1], x2 = emb[ei + 2];
            float x3 = fmaf(fw0, f0, fmaf(fw1, f1, fmaf(fw2, f2v, fb0)));
            float x4 = fmaf(fw3, f0, fmaf(fw4, f1, fmaf(fw5, f2v, fb1)));
            float x5 = fmaf(fw6, f0, fmaf(fw7, f1, fmaf(fw8, f2v, fb2)));
            lds.x[t][0][ee] = pk_h16(x0, x1);
            lds.x[t][1][ee] = pk_h16(x2, x3);
            lds.x[t][2][ee] = pk_h16(x4, x5);
            lds.m[t][ee]    = (f1 != 0.f) ? 1.f : 0.f;
        }
    }

    const u32x4* wv = (const u32x4*)wsr;
    const f32x16 zf = {};                       // persistent zero C-fragment

    // ---- Phase 1: layer-0 forward (x-MFMAs pipelined one step ahead) ----
    {
        u32x4 wf0 = wv[0 * 64 + lane], wf1 = wv[1 * 64 + lane];
        u32x4 wf2 = wv[2 * 64 + lane], wf3 = wv[3 * 64 + lane];
        float cf[5] = {0,0,0,0,0}, hv[5] = {0,0,0,0,0};
        u32x4 bx0;
        {
            u32 x01 = lds.x[0][0][e], x23 = lds.x[0][1][e], x45 = lds.x[0][2][e];
            bx0[0] = hi ? x45 : x01; bx0[1] = hi ? PK1 : x23; bx0[2] = 0u; bx0[3] = 0u;
        }
        f32x16 a0x = MFMA(wf0, bx0, zf);
        f32x16 a1x = MFMA(wf2, bx0, zf);
#pragma unroll 1
        for (int t = 0; t < TT; ++t) {
            u32x4 bh = pack_h(hv, hi, xaddr, 0u);
            f32x16 a0 = MFMA(wf1, bh, a0x);
            f32x16 a1 = MFMA(wf3, bh, a1x);
            if (t + 1 < TT) {                    // independent next-t x-contribution
                u32 x01 = lds.x[t+1][0][e], x23 = lds.x[t+1][1][e], x45 = lds.x[t+1][2][e];
                u32x4 bx; bx[0] = hi ? x45 : x01; bx[1] = hi ? PK1 : x23; bx[2] = 0u; bx[3] = 0u;
                a0x = MFMA(wf0, bx, zf);
                a1x = MFMA(wf2, bx, zf);
            }
            cell_update5(a0, a1, cf, hv);
            u32x4 st = pack_h(hv, hi, xaddr, 0u);
            if (WS) {
                *(uint2*)(hfp + t * 160 + lane * 2) = make_uint2(st[0], st[1]);
                if (!hi) hfp[t * 160 + 128 + e] = st[2];
            } else {
                lds.hf[t][lane * 2] = st[0]; lds.hf[t][lane * 2 + 1] = st[1];
                if (!hi) lds.hf[t][128 + e] = st[2];
            }
        }
    }

    // ---- Phase 2: pipelined  cellB(t) || cellA(t-1)  (independent given cellA(t)) ----
    {
        u32x4 wb0 = wv[4 * 64 + lane], wb1 = wv[5 * 64 + lane];
        u32x4 wb2 = wv[6 * 64 + lane], wb3 = wv[7 * 64 + lane];
        u32x4 wB0 = wv[8 * 64 + lane], wB1 = wv[9 * 64 + lane], wB2 = wv[10 * 64 + lane];
        u32x4 wB3 = wv[11 * 64 + lane], wB4 = wv[12 * 64 + lane], wB5 = wv[13 * 64 + lane];
        float cb[5] = {0,0,0,0,0}, hbv[5] = {0,0,0,0,0};
        float cc[5] = {0,0,0,0,0}, h1v[5] = {0,0,0,0,0};
        float tot = 0.f;

        // prologue: cellA(19) with hb(20)=0 (h-MFMAs skipped: contribution is 0)
        {
            u32 x01 = lds.x[TT-1][0][e], x23 = lds.x[TT-1][1][e], x45 = lds.x[TT-1][2][e];
            u32x4 bx; bx[0] = hi ? x45 : x01; bx[1] = hi ? PK1 : x23; bx[2] = 0u; bx[3] = 0u;
            f32x16 a0 = MFMA(wb0, bx, zf);
            f32x16 a1 = MFMA(wb2, bx, zf);
            cell_update5(a0, a1, cb, hbv);
        }
        uint2 cur2; u32 curw;
        if (WS) { cur2 = *(const uint2*)(hfp + (TT-1) * 160 + lane * 2);
                  curw = hfp[(TT-1) * 160 + 128 + e]; }
        else    { cur2 = make_uint2(lds.hf[TT-1][lane * 2], lds.hf[TT-1][lane * 2 + 1]);
                  curw = lds.hf[TT-1][128 + e]; }

#pragma unroll 1
        for (int t = TT - 1; t >= 1; --t) {
            uint2 nxt2; u32 nxtw;                // prefetch hf0(t-1)
            if (WS) { nxt2 = *(const uint2*)(hfp + (t-1) * 160 + lane * 2);
                      nxtw = hfp[(t-1) * 160 + 128 + e]; }
            else    { nxt2 = make_uint2(lds.hf[t-1][lane * 2], lds.hf[t-1][lane * 2 + 1]);
                      nxtw = lds.hf[t-1][128 + e]; }
            // shared h-fragment: cellB's hb-input == cellA(t-1)'s h-input
            u32x4 shared = pack_h(hbv, hi, xaddr, 0u);
            u32x4 bh1    = pack_h(h1v, hi, xaddr, hi ? 0u : PK1);
            u32x4 bhf; bhf[0] = cur2.x; bhf[1] = cur2.y; bhf[2] = hi ? 0u : curw; bhf[3] = 0u;
            // cellB(t): layer-1 backward
            f32x16 B0 = MFMA(wB0, bhf, zf); B0 = MFMA(wB1, shared, B0); B0 = MFMA(wB2, bh1, B0);
            f32x16 B1 = MFMA(wB3, bhf, zf); B1 = MFMA(wB4, shared, B1); B1 = MFMA(wB5, bh1, B1);
            // cellA(t-1): layer-0 backward
            u32 x01 = lds.x[t-1][0][e], x23 = lds.x[t-1][1][e], x45 = lds.x[t-1][2][e];
            u32x4 bx; bx[0] = hi ? x45 : x01; bx[1] = hi ? PK1 : x23; bx[2] = 0u; bx[3] = 0u;
            f32x16 A0 = MFMA(wb0, bx, zf); A0 = MFMA(wb1, shared, A0);
            f32x16 A1 = MFMA(wb2, bx, zf); A1 = MFMA(wb3, shared, A1);
            // updates (independent chains; compiler interleaves)
            cell_update5(B0, B1, cc, h1v);
            if (hi) {
                float ip = fmaxf(h1v[4] * lds.m[t][e], 0.f);
                out[BB + (b0 + e) * TT + t] = ip;
                tot += ip;
            }
            cell_update5(A0, A1, cb, hbv);
            cur2 = nxt2; curw = nxtw;
        }
        // epilogue: cellB(0)
        {
            u32x4 shared = pack_h(hbv, hi, xaddr, 0u);
            u32x4 bh1    = pack_h(h1v, hi, xaddr, hi ? 0u : PK1);
            u32x4 bhf; bhf[0] = cur2.x; bhf[1] = cur2.y; bhf[2] = hi ? 0u : curw; bhf[3] = 0u;
            f32x16 B0 = MFMA(wB0, bhf, zf); B0 = MFMA(wB1, shared, B0); B0 = MFMA(wB2, bh1, B0);
            f32x16 B1 = MFMA(wB3, bhf, zf); B1 = MFMA(wB4, shared, B1); B1 = MFMA(wB5, bh1, B1);
            cell_update5(B0, B1, cc, h1v);
            if (hi) {
                float ip = fmaxf(h1v[4] * lds.m[0][e], 0.f);
                out[BB + (b0 + e) * TT + 0] = ip;
                tot += ip;
                out[b0 + e] = tot;
            }
        }
    }
}

extern "C" void kernel_launch(void* const* d_in, const int* in_sizes, int n_in,
                              void* d_out, int out_size, void* d_ws, size_t ws_size,
                              hipStream_t stream) {
    const int*   eidx  = (const int*)  d_in[0];
    const float* f     = (const float*)d_in[1];
    const float* emb   = (const float*)d_in[2];
    const float* fw    = (const float*)d_in[3];
    const float* fb    = (const float*)d_in[4];
    const float* wih0  = (const float*)d_in[5];
    const float* whh0  = (const float*)d_in[6];
    const float* bih0  = (const float*)d_in[7];
    const float* bhh0  = (const float*)d_in[8];
    const float* wih0r = (const float*)d_in[9];
    const float* whh0r = (const float*)d_in[10];
    const float* bih0r = (const float*)d_in[11];
    const float* bhh0r = (const float*)d_in[12];
    // d_in[13..16] = layer-1 forward weights: dead (output uses only bwd unit 9)
    const float* wih1r = (const float*)d_in[17];
    const float* whh1r = (const float*)d_in[18];
    const float* bih1r = (const float*)d_in[19];
    const float* bhh1r = (const float*)d_in[20];
    float* out = (float*)d_out;
    u32* ws = (u32*)d_ws;

    hipLaunchKernelGGL(prep_mfma, dim3(1), dim3(256), 0, stream,
                       wih0, whh0, bih0, bhh0, wih0r, whh0r, bih0r, bhh0r,
                       wih1r, whh1r, bih1r, bhh1r, ws);

    const size_t need = (size_t)(WS_HF0 + (size_t)NBLK * TT * 160) * 4;
    dim3 grid(NBLK), block(64);
    if (ws_size >= need) {
        hipLaunchKernelGGL(bilstm_mfma<true>, grid, block, 0, stream,
                           eidx, f, emb, fw, fb, ws, ws + WS_HF0, out);
    } else {
        hipLaunchKernelGGL(bilstm_mfma<false>, grid, block, 0, stream,
                           eidx, f, emb, fw, fb, ws, ws + WS_HF0, out);
    }
}